// Round 8
// baseline (3450.017 us; speedup 1.0000x reference)
//
#include <hip/hip_runtime.h>
#include <cstddef>
#include <cstdint>

#define NB 64
#define ND 1024
#define NO 31
#define NSTEPS 16
#define KS 62            // k-splits in P (k-chunk = 512 k-units, never crosses an opcode)
#define KT32 992         // total K32 steps = 31*1024/32
#define KC32 16          // K32 steps per block (two 8-step halves, one per wave-pair)
#define GRID_P 248       // persistent grid = 4 n-tiles * 62 k-splits (<= 256 CUs, co-resident)

typedef _Float16 half8 __attribute__((ext_vector_type(8)));
typedef float floatx4 __attribute__((ext_vector_type(4)));

// ---------------- softmax over opcode logits: W[b][t][o]; also zero barrier ----
__global__ void softmax_k(const float* __restrict__ logits, float* __restrict__ W,
                          unsigned* __restrict__ barcnt) {
    if (blockIdx.x == 0 && threadIdx.x == 0) *barcnt = 0u;   // re-init every replay
    int row = blockIdx.x * blockDim.x + threadIdx.x;  // row = b*16 + t
    if (row >= NB * NSTEPS) return;
    const float* x = logits + (size_t)row * NO;
    float m = -1e30f;
    for (int o = 0; o < NO; ++o) m = fmaxf(m, x[o]);
    float e[NO]; float s = 0.f;
    for (int o = 0; o < NO; ++o) { e[o] = expf(x[o] - m); s += e[o]; }
    float inv = 1.0f / s;
    float* wo = W + (size_t)row * NO;
    for (int o = 0; o < NO; ++o) wo[o] = e[o] * inv;
}

// ---- kconv v2: coalesced tile transpose (unchanged, verified) ----
__global__ __launch_bounds__(256) void kconv_k(const float* __restrict__ K,
                                               _Float16* __restrict__ Ktf) {
    __shared__ float tile[32 * 256];           // 32 KB, swizzled cols
    int kt  = blockIdx.x >> 2;                 // 0..991
    int nb4 = blockIdx.x & 3;                  // 0..3 (256-col tile)
    int tid = threadIdx.x;
    int lane = tid & 63, w = tid >> 6;

    {
        const float* src = K + ((size_t)kt * 32) * ND + nb4 * 256;
        #pragma unroll
        for (int i = 0; i < 8; ++i) {
            int r = i * 4 + w;
            int x = lane * 4;
            int xs = x ^ (((r >> 3) & 1) << 4);
            float4 v = *(const float4*)(src + (size_t)r * ND + x);
            *(float4*)&tile[r * 256 + xs] = v;
        }
    }
    __syncthreads();

    int kl0 = (lane >> 4) * 8;
    int swz = ((lane >> 4) & 1) << 4;
    #pragma unroll
    for (int i = 0; i < 4; ++i) {
        int ns_local = i * 4 + w;
        int nl = ns_local * 16 + (lane & 15);
        int xsw = nl ^ swz;
        half8 v;
        #pragma unroll
        for (int j = 0; j < 8; ++j) v[j] = (_Float16)tile[(kl0 + j) * 256 + xsw];
        int ns = nb4 * 16 + ns_local;
        size_t unit = ((size_t)ns * KT32 + kt) * 64 + lane;
        *(half8*)(Ktf + unit * 8) = v;
    }
}

// ---- device-scope grid barrier (monotonic epoch; all GRID_P blocks resident) ----
__device__ __forceinline__ void gbar(unsigned* cnt, unsigned target) {
    __threadfence();                 // release: drain this block's stores device-wide
    __syncthreads();
    if (threadIdx.x == 0) {
        atomicAdd(cnt, 1u);          // device-scope by default (m20)
        while (__hip_atomic_load(cnt, __ATOMIC_RELAXED, __HIP_MEMORY_SCOPE_AGENT) < target)
            __builtin_amdgcn_s_sleep(2);
    }
    __syncthreads();
    __threadfence();                 // acquire
}

// ---- persistent fused step loop: R5 gemm body + R6 barrier/update ----
// 248 blocks x 512 thr. Block (nb,ks) owns n-tile nb (256 cols) and k-chunk ks
// (512 k-units). B is RE-STREAMED from L3 each step (live range inside the step
// -> no spill; R6's cross-step pinning was the failure). Per step:
// stage A -> preload B(32 frags) -> MFMA -> pair-reduce -> P store
// -> grid barrier -> distributed update -> grid barrier.
__global__ __launch_bounds__(512) void fused_k(
    const float* __restrict__ signal, const _Float16* __restrict__ Ktf,
    const float* __restrict__ W, const float* __restrict__ operands,
    float* __restrict__ P, float* __restrict__ h0, float* __restrict__ h1,
    float* __restrict__ out, unsigned* __restrict__ barcnt)
{
    __shared__ _Float16 lds_a[64 * 512];   // 64 KiB; A tile, reused as reduce buf
    int bid = blockIdx.x;                  // 0..247
    int nb = bid & 3, ks = bid >> 2;
    int tid = threadIdx.x;                 // 0..511
    int l = tid & 63, w = tid >> 6;        // w 0..7
    int o = ks >> 1;
    int d_base = (ks & 1) * 512;
    int ml = l & 15, q = l >> 4;
    int wn = w & 3, kh = w >> 2;
    int ns0 = nb * 16 + wn * 4;
    int sb = tid >> 3, su = tid & 7;       // A-staging ids
    int gtid = bid * 512 + tid;            // update-phase id

    unsigned bar = 0;
    const float* hc = signal;
    float* hn = h0;

    for (int t = 0; t < NSTEPS; ++t) {
        // ---- stage A: fp32 h * w -> fp16, frag-ordered (64 b x 512 d) ----
        {
            float wv = W[((size_t)sb * NSTEPS + t) * NO + o];
            const float* hb = hc + (size_t)sb * ND + d_base;
            #pragma unroll
            for (int li = 0; li < 8; ++li) {
                int p = li * 8 + su;
                float4 x0 = *(const float4*)(hb + p * 8);
                float4 x1 = *(const float4*)(hb + p * 8 + 4);
                half8 v;
                v[0] = (_Float16)(x0.x * wv); v[1] = (_Float16)(x0.y * wv);
                v[2] = (_Float16)(x0.z * wv); v[3] = (_Float16)(x0.w * wv);
                v[4] = (_Float16)(x1.x * wv); v[5] = (_Float16)(x1.y * wv);
                v[6] = (_Float16)(x1.z * wv); v[7] = (_Float16)(x1.w * wv);
                *(half8*)&lds_a[(size_t)(p * 64 + sb) * 8] = v;
            }
        }
        __syncthreads();

        // ---- preload B for this wave's k-half (step-local live range) ----
        half8 breg[4][8];
        #pragma unroll
        for (int tt = 0; tt < 4; ++tt) {
            const half8* bp = (const half8*)Ktf
                + ((size_t)(ns0 + tt) * KT32 + (size_t)(ks * KC32 + kh * 8)) * 64 + l;
            #pragma unroll
            for (int s = 0; s < 8; ++s) breg[tt][s] = bp[(size_t)s * 64];
        }

        floatx4 acc[4][4] = {};
        const half8* Ap = (const half8*)lds_a;
        #pragma unroll
        for (int s = 0; s < 8; ++s) {
            int abase = ((kh * 8 + s) * 4 + q) * 64 + ml;
            half8 a0 = Ap[abase];
            half8 a1 = Ap[abase + 16];
            half8 a2 = Ap[abase + 32];
            half8 a3 = Ap[abase + 48];
            #pragma unroll
            for (int tt = 0; tt < 4; ++tt) {
                acc[tt][0] = __builtin_amdgcn_mfma_f32_16x16x32_f16(a0, breg[tt][s], acc[tt][0], 0, 0, 0);
                acc[tt][1] = __builtin_amdgcn_mfma_f32_16x16x32_f16(a1, breg[tt][s], acc[tt][1], 0, 0, 0);
                acc[tt][2] = __builtin_amdgcn_mfma_f32_16x16x32_f16(a2, breg[tt][s], acc[tt][2], 0, 0, 0);
                acc[tt][3] = __builtin_amdgcn_mfma_f32_16x16x32_f16(a3, breg[tt][s], acc[tt][3], 0, 0, 0);
            }
        }

        // ---- pairwise k-half reduce via LDS (reuse lds_a) ----
        __syncthreads();
        floatx4* lred = (floatx4*)lds_a;
        if (kh == 1) {
            #pragma unroll
            for (int tt = 0; tt < 4; ++tt)
                #pragma unroll
                for (int mt = 0; mt < 4; ++mt)
                    lred[(tt * 4 + mt) * 256 + wn * 64 + l] = acc[tt][mt];
        }
        __syncthreads();
        if (kh == 0) {
            // C/D mapping: col = l&15, row = (l>>4)*4 + r (verified)
            float* Pks = P + (size_t)ks * (NB * ND);
            #pragma unroll
            for (int tt = 0; tt < 4; ++tt) {
                int n = (ns0 + tt) * 16 + ml;
                #pragma unroll
                for (int mt = 0; mt < 4; ++mt) {
                    floatx4 other = lred[(tt * 4 + mt) * 256 + wn * 64 + l];
                    #pragma unroll
                    for (int r = 0; r < 4; ++r) {
                        int b = mt * 16 + q * 4 + r;
                        Pks[(size_t)b * ND + n] = acc[tt][mt][r] + other[r];
                    }
                }
            }
        }

        // ---- barrier: P complete ----
        bar += GRID_P; gbar(barcnt, bar);

        // ---- distributed update: one thread per output (first 65536 threads) ----
        float* dst = (t == NSTEPS - 1) ? out : hn;
        if (gtid < NB * ND) {
            int b = gtid >> 10;
            const float* pp = P + gtid;
            float a0 = 0.f, a1 = 0.f, a2 = 0.f, a3 = 0.f;
            float a4 = 0.f, a5 = 0.f, a6 = 0.f, a7 = 0.f;
            #pragma unroll
            for (int i = 0; i < 56; i += 8) {
                a0 += pp[(size_t)(i + 0) * (NB * ND)];
                a1 += pp[(size_t)(i + 1) * (NB * ND)];
                a2 += pp[(size_t)(i + 2) * (NB * ND)];
                a3 += pp[(size_t)(i + 3) * (NB * ND)];
                a4 += pp[(size_t)(i + 4) * (NB * ND)];
                a5 += pp[(size_t)(i + 5) * (NB * ND)];
                a6 += pp[(size_t)(i + 6) * (NB * ND)];
                a7 += pp[(size_t)(i + 7) * (NB * ND)];
            }
            a0 += pp[(size_t)56 * (NB * ND)];
            a1 += pp[(size_t)57 * (NB * ND)];
            a2 += pp[(size_t)58 * (NB * ND)];
            a3 += pp[(size_t)59 * (NB * ND)];
            a4 += pp[(size_t)60 * (NB * ND)];
            a5 += pp[(size_t)61 * (NB * ND)];
            float tot = ((a0 + a1) + (a2 + a3)) + ((a4 + a5) + (a6 + a7));
            float gl = operands[((size_t)b * NSTEPS + t) * 4 + 3];
            float gt = 1.0f / (1.0f + expf(-gl));
            dst[gtid] = gt * tot + (1.0f - gt) * hc[gtid];
        }

        // ---- barrier: h complete (skip after final step) ----
        if (t < NSTEPS - 1) { bar += GRID_P; gbar(barcnt, bar); }

        hc = dst;
        hn = (hn == h0) ? h1 : h0;
    }
}

extern "C" void kernel_launch(void* const* d_in, const int* in_sizes, int n_in,
                              void* d_out, int out_size, void* d_ws, size_t ws_size,
                              hipStream_t stream)
{
    const float* logits   = (const float*)d_in[0];  // (64,16,31)
    const float* operands = (const float*)d_in[1];  // (64,16,4)
    const float* signal   = (const float*)d_in[2];  // (64,1024)
    const float* opk      = (const float*)d_in[3];  // (31,1024,1024)
    float* out = (float*)d_out;
    char* ws = (char*)d_ws;

    size_t offW   = 0;                                 // W: 126,976 B
    size_t offBar = 126976;                            // barrier counter (4 B)
    size_t offP   = 131072;                            // P: KS*64*1024*4 = 15.5 MB
    size_t offH   = offP + (size_t)KS * NB * ND * 4;
    size_t offK   = offH + 2ull * NB * ND * 4;         // Ktf: 62 MiB fp16

    float*    W   = (float*)(ws + offW);
    unsigned* bc  = (unsigned*)(ws + offBar);
    float*    P   = (float*)(ws + offP);
    float*    h0  = (float*)(ws + offH);
    float*    h1  = h0 + NB * ND;
    _Float16* Ktf = (_Float16*)(ws + offK);

    softmax_k<<<dim3(4), 256, 0, stream>>>(logits, W, bc);
    kconv_k<<<dim3(3968), 256, 0, stream>>>(opk, Ktf);
    fused_k<<<dim3(GRID_P), 512, 0, stream>>>(signal, Ktf, W, operands,
                                              P, h0, h1, out, bc);
}

// Round 9
// 2009.796 us; speedup vs baseline: 1.7166x; 1.7166x over previous
//
#include <hip/hip_runtime.h>
#include <cstddef>
#include <cstdint>

#define NB 64
#define ND 1024
#define NO 31
#define NSTEPS 16
#define KS 62            // k-splits in P (k-chunk = 512 k-units, never crosses an opcode)
#define KT32 992         // total K32 steps = 31*1024/32
#define KC32 16          // K32 steps per block (streamed by each wave)
#define GRID_P 248       // persistent grid = 4 n-tiles * 62 k-splits
#define THR_P 256        // 4 waves -> larger VGPR budget (512-thr caps at 128: R6/R8)

typedef _Float16 half8 __attribute__((ext_vector_type(8)));
typedef float floatx4 __attribute__((ext_vector_type(4)));

// ---------------- softmax over opcode logits: W[b][t][o]; also zero barrier ----
__global__ void softmax_k(const float* __restrict__ logits, float* __restrict__ W,
                          unsigned* __restrict__ barcnt) {
    if (blockIdx.x == 0 && threadIdx.x == 0) *barcnt = 0u;   // re-init every replay
    int row = blockIdx.x * blockDim.x + threadIdx.x;  // row = b*16 + t
    if (row >= NB * NSTEPS) return;
    const float* x = logits + (size_t)row * NO;
    float m = -1e30f;
    for (int o = 0; o < NO; ++o) m = fmaxf(m, x[o]);
    float e[NO]; float s = 0.f;
    for (int o = 0; o < NO; ++o) { e[o] = expf(x[o] - m); s += e[o]; }
    float inv = 1.0f / s;
    float* wo = W + (size_t)row * NO;
    for (int o = 0; o < NO; ++o) wo[o] = e[o] * inv;
}

// ---- kconv v2: coalesced tile transpose (unchanged, verified) ----
__global__ __launch_bounds__(256) void kconv_k(const float* __restrict__ K,
                                               _Float16* __restrict__ Ktf) {
    __shared__ float tile[32 * 256];           // 32 KB, swizzled cols
    int kt  = blockIdx.x >> 2;                 // 0..991
    int nb4 = blockIdx.x & 3;                  // 0..3 (256-col tile)
    int tid = threadIdx.x;
    int lane = tid & 63, w = tid >> 6;

    {
        const float* src = K + ((size_t)kt * 32) * ND + nb4 * 256;
        #pragma unroll
        for (int i = 0; i < 8; ++i) {
            int r = i * 4 + w;
            int x = lane * 4;
            int xs = x ^ (((r >> 3) & 1) << 4);
            float4 v = *(const float4*)(src + (size_t)r * ND + x);
            *(float4*)&tile[r * 256 + xs] = v;
        }
    }
    __syncthreads();

    int kl0 = (lane >> 4) * 8;
    int swz = ((lane >> 4) & 1) << 4;
    #pragma unroll
    for (int i = 0; i < 4; ++i) {
        int ns_local = i * 4 + w;
        int nl = ns_local * 16 + (lane & 15);
        int xsw = nl ^ swz;
        half8 v;
        #pragma unroll
        for (int j = 0; j < 8; ++j) v[j] = (_Float16)tile[(kl0 + j) * 256 + xsw];
        int ns = nb4 * 16 + ns_local;
        size_t unit = ((size_t)ns * KT32 + kt) * 64 + lane;
        *(half8*)(Ktf + unit * 8) = v;
    }
}

// ---- device-scope grid barrier (monotonic epoch; all GRID_P blocks resident) ----
__device__ __forceinline__ void gbar(unsigned* cnt, unsigned target) {
    __threadfence();                 // release
    __syncthreads();
    if (threadIdx.x == 0) {
        atomicAdd(cnt, 1u);          // device-scope by default (m20)
        while (__hip_atomic_load(cnt, __ATOMIC_RELAXED, __HIP_MEMORY_SCOPE_AGENT) < target)
            __builtin_amdgcn_s_sleep(2);
    }
    __syncthreads();
    __threadfence();                 // acquire
}

// ---- persistent fused step loop: R7 streaming gemm body + R6 barrier/update ----
// 248 blocks x 256 thr (4 waves). Block (nb,ks) owns n-tile nb (256 cols) and
// k-chunk ks (512 k-units). Wave = M64 x N64, streams 16 K32 steps with 1-deep
// B prefetch (~32 live B VGPRs -> no spill at the 256-thr register budget).
__global__ __launch_bounds__(THR_P) void fused_k(
    const float* __restrict__ signal, const _Float16* __restrict__ Ktf,
    const float* __restrict__ W, const float* __restrict__ operands,
    float* __restrict__ P, float* __restrict__ h0, float* __restrict__ h1,
    float* __restrict__ out, unsigned* __restrict__ barcnt)
{
    __shared__ _Float16 lds_a[64 * 512];   // 64 KiB A tile
    int bid = blockIdx.x;                  // 0..247
    int nb = bid & 3, ks = bid >> 2;
    int tid = threadIdx.x;                 // 0..255
    int l = tid & 63, w = tid >> 6;        // w 0..3
    int o = ks >> 1;
    int d_base = (ks & 1) * 512;
    int ml = l & 15, q = l >> 4;
    int ns0 = nb * 16 + w * 4;             // four n-subtiles of 16 per wave
    int sb = tid >> 2, su = tid & 3;       // A-staging ids
    int gtid = bid * THR_P + tid;          // update-phase id

    // loop-invariant B stream pointers
    const half8* bp0 = (const half8*)Ktf + ((size_t)(ns0 + 0) * KT32 + (size_t)ks * KC32) * 64 + l;
    const half8* bp1 = (const half8*)Ktf + ((size_t)(ns0 + 1) * KT32 + (size_t)ks * KC32) * 64 + l;
    const half8* bp2 = (const half8*)Ktf + ((size_t)(ns0 + 2) * KT32 + (size_t)ks * KC32) * 64 + l;
    const half8* bp3 = (const half8*)Ktf + ((size_t)(ns0 + 3) * KT32 + (size_t)ks * KC32) * 64 + l;

    unsigned bar = 0;
    const float* hc = signal;
    float* hn = h0;

    for (int t = 0; t < NSTEPS; ++t) {
        // ---- first B fragments issued early (hide under A staging) ----
        half8 bc0 = bp0[0], bc1 = bp1[0], bc2 = bp2[0], bc3 = bp3[0];

        // ---- stage A: fp32 h * w -> fp16, frag-ordered (64 b x 512 d) ----
        {
            float wv = W[((size_t)sb * NSTEPS + t) * NO + o];
            const float* hb = hc + (size_t)sb * ND + d_base;
            #pragma unroll
            for (int li = 0; li < 16; ++li) {
                int p = li * 4 + su;
                float4 x0 = *(const float4*)(hb + p * 8);
                float4 x1 = *(const float4*)(hb + p * 8 + 4);
                half8 v;
                v[0] = (_Float16)(x0.x * wv); v[1] = (_Float16)(x0.y * wv);
                v[2] = (_Float16)(x0.z * wv); v[3] = (_Float16)(x0.w * wv);
                v[4] = (_Float16)(x1.x * wv); v[5] = (_Float16)(x1.y * wv);
                v[6] = (_Float16)(x1.z * wv); v[7] = (_Float16)(x1.w * wv);
                *(half8*)&lds_a[(size_t)(p * 64 + sb) * 8] = v;
            }
        }
        __syncthreads();

        const half8* Ap = (const half8*)lds_a;
        floatx4 acc[4][4] = {};
        #pragma unroll
        for (int s = 0; s < KC32; ++s) {
            half8 bn0, bn1, bn2, bn3;
            if (s < KC32 - 1) {                    // prefetch next k-step
                bn0 = bp0[(size_t)(s + 1) * 64];
                bn1 = bp1[(size_t)(s + 1) * 64];
                bn2 = bp2[(size_t)(s + 1) * 64];
                bn3 = bp3[(size_t)(s + 1) * 64];
            }
            int abase = (s * 4 + q) * 64 + ml;
            half8 a0 = Ap[abase];
            half8 a1 = Ap[abase + 16];
            half8 a2 = Ap[abase + 32];
            half8 a3 = Ap[abase + 48];
            acc[0][0] = __builtin_amdgcn_mfma_f32_16x16x32_f16(a0, bc0, acc[0][0], 0, 0, 0);
            acc[0][1] = __builtin_amdgcn_mfma_f32_16x16x32_f16(a1, bc0, acc[0][1], 0, 0, 0);
            acc[0][2] = __builtin_amdgcn_mfma_f32_16x16x32_f16(a2, bc0, acc[0][2], 0, 0, 0);
            acc[0][3] = __builtin_amdgcn_mfma_f32_16x16x32_f16(a3, bc0, acc[0][3], 0, 0, 0);
            acc[1][0] = __builtin_amdgcn_mfma_f32_16x16x32_f16(a0, bc1, acc[1][0], 0, 0, 0);
            acc[1][1] = __builtin_amdgcn_mfma_f32_16x16x32_f16(a1, bc1, acc[1][1], 0, 0, 0);
            acc[1][2] = __builtin_amdgcn_mfma_f32_16x16x32_f16(a2, bc1, acc[1][2], 0, 0, 0);
            acc[1][3] = __builtin_amdgcn_mfma_f32_16x16x32_f16(a3, bc1, acc[1][3], 0, 0, 0);
            acc[2][0] = __builtin_amdgcn_mfma_f32_16x16x32_f16(a0, bc2, acc[2][0], 0, 0, 0);
            acc[2][1] = __builtin_amdgcn_mfma_f32_16x16x32_f16(a1, bc2, acc[2][1], 0, 0, 0);
            acc[2][2] = __builtin_amdgcn_mfma_f32_16x16x32_f16(a2, bc2, acc[2][2], 0, 0, 0);
            acc[2][3] = __builtin_amdgcn_mfma_f32_16x16x32_f16(a3, bc2, acc[2][3], 0, 0, 0);
            acc[3][0] = __builtin_amdgcn_mfma_f32_16x16x32_f16(a0, bc3, acc[3][0], 0, 0, 0);
            acc[3][1] = __builtin_amdgcn_mfma_f32_16x16x32_f16(a1, bc3, acc[3][1], 0, 0, 0);
            acc[3][2] = __builtin_amdgcn_mfma_f32_16x16x32_f16(a2, bc3, acc[3][2], 0, 0, 0);
            acc[3][3] = __builtin_amdgcn_mfma_f32_16x16x32_f16(a3, bc3, acc[3][3], 0, 0, 0);
            if (s < KC32 - 1) { bc0 = bn0; bc1 = bn1; bc2 = bn2; bc3 = bn3; }
        }

        // ---- epilogue: C/D col = l&15, row = (l>>4)*4 + r (verified mapping) ----
        {
            float* Pks = P + (size_t)ks * (NB * ND);
            #pragma unroll
            for (int tt = 0; tt < 4; ++tt) {
                int n = (ns0 + tt) * 16 + ml;
                #pragma unroll
                for (int mt = 0; mt < 4; ++mt) {
                    #pragma unroll
                    for (int r = 0; r < 4; ++r) {
                        int b = mt * 16 + q * 4 + r;
                        Pks[(size_t)b * ND + n] = acc[tt][mt][r];
                    }
                }
            }
        }

        // ---- barrier: P complete ----
        bar += GRID_P; gbar(barcnt, bar);

        // ---- distributed update: grid-stride over 65536 outputs ----
        float* dst = (t == NSTEPS - 1) ? out : hn;
        for (int g = gtid; g < NB * ND; g += GRID_P * THR_P) {
            int b = g >> 10;
            const float* pp = P + g;
            float a0 = 0.f, a1 = 0.f, a2 = 0.f, a3 = 0.f;
            float a4 = 0.f, a5 = 0.f, a6 = 0.f, a7 = 0.f;
            #pragma unroll
            for (int i = 0; i < 56; i += 8) {
                a0 += pp[(size_t)(i + 0) * (NB * ND)];
                a1 += pp[(size_t)(i + 1) * (NB * ND)];
                a2 += pp[(size_t)(i + 2) * (NB * ND)];
                a3 += pp[(size_t)(i + 3) * (NB * ND)];
                a4 += pp[(size_t)(i + 4) * (NB * ND)];
                a5 += pp[(size_t)(i + 5) * (NB * ND)];
                a6 += pp[(size_t)(i + 6) * (NB * ND)];
                a7 += pp[(size_t)(i + 7) * (NB * ND)];
            }
            a0 += pp[(size_t)56 * (NB * ND)];
            a1 += pp[(size_t)57 * (NB * ND)];
            a2 += pp[(size_t)58 * (NB * ND)];
            a3 += pp[(size_t)59 * (NB * ND)];
            a4 += pp[(size_t)60 * (NB * ND)];
            a5 += pp[(size_t)61 * (NB * ND)];
            float tot = ((a0 + a1) + (a2 + a3)) + ((a4 + a5) + (a6 + a7));
            float gl = operands[((size_t)b * NSTEPS + t) * 4 + 3];
            float gt = 1.0f / (1.0f + expf(-gl));
            dst[g] = gt * tot + (1.0f - gt) * hc[g];
        }

        // ---- barrier: h complete (skip after final step) ----
        if (t < NSTEPS - 1) { bar += GRID_P; gbar(barcnt, bar); }

        hc = dst;
        hn = (hn == h0) ? h1 : h0;
    }
}

extern "C" void kernel_launch(void* const* d_in, const int* in_sizes, int n_in,
                              void* d_out, int out_size, void* d_ws, size_t ws_size,
                              hipStream_t stream)
{
    const float* logits   = (const float*)d_in[0];  // (64,16,31)
    const float* operands = (const float*)d_in[1];  // (64,16,4)
    const float* signal   = (const float*)d_in[2];  // (64,1024)
    const float* opk      = (const float*)d_in[3];  // (31,1024,1024)
    float* out = (float*)d_out;
    char* ws = (char*)d_ws;

    size_t offW   = 0;                                 // W: 126,976 B
    size_t offBar = 126976;                            // barrier counter (4 B)
    size_t offP   = 131072;                            // P: KS*64*1024*4 = 15.5 MB
    size_t offH   = offP + (size_t)KS * NB * ND * 4;
    size_t offK   = offH + 2ull * NB * ND * 4;         // Ktf: 62 MiB fp16

    float*    W   = (float*)(ws + offW);
    unsigned* bc  = (unsigned*)(ws + offBar);
    float*    P   = (float*)(ws + offP);
    float*    h0  = (float*)(ws + offH);
    float*    h1  = h0 + NB * ND;
    _Float16* Ktf = (_Float16*)(ws + offK);

    softmax_k<<<dim3(4), 256, 0, stream>>>(logits, W, bc);
    kconv_k<<<dim3(3968), 256, 0, stream>>>(opk, Ktf);
    fused_k<<<dim3(GRID_P), THR_P, 0, stream>>>(signal, Ktf, W, operands,
                                                P, h0, h1, out, bc);
}

// Round 10
// 539.888 us; speedup vs baseline: 6.3902x; 3.7226x over previous
//
#include <hip/hip_runtime.h>
#include <cstddef>
#include <cstdint>

#define NB 64
#define ND 1024
#define NO 31
#define NSTEPS 16
#define KS 31            // one P slice per opcode (k-chunk = 1024)
#define KT32 992         // total K32 steps = 31*1024/32

typedef _Float16 half8 __attribute__((ext_vector_type(8)));
typedef float floatx4 __attribute__((ext_vector_type(4)));

// ---------------- softmax over opcode logits: W[b][t][o] ----------------
__global__ void softmax_k(const float* __restrict__ logits, float* __restrict__ W) {
    int row = blockIdx.x * blockDim.x + threadIdx.x;  // row = b*16 + t
    if (row >= NB * NSTEPS) return;
    const float* x = logits + (size_t)row * NO;
    float m = -1e30f;
    for (int o = 0; o < NO; ++o) m = fmaxf(m, x[o]);
    float e[NO]; float s = 0.f;
    for (int o = 0; o < NO; ++o) { e[o] = expf(x[o] - m); s += e[o]; }
    float inv = 1.0f / s;
    float* wo = W + (size_t)row * NO;
    for (int o = 0; o < NO; ++o) wo[o] = e[o] * inv;
}

// ---- kconv v2: coalesced tile transpose (unchanged, verified) ----
__global__ __launch_bounds__(256) void kconv_k(const float* __restrict__ K,
                                               _Float16* __restrict__ Ktf) {
    __shared__ float tile[32 * 256];           // 32 KB, swizzled cols
    int kt  = blockIdx.x >> 2;                 // 0..991
    int nb4 = blockIdx.x & 3;                  // 0..3 (256-col tile)
    int tid = threadIdx.x;
    int lane = tid & 63, w = tid >> 6;

    {
        const float* src = K + ((size_t)kt * 32) * ND + nb4 * 256;
        #pragma unroll
        for (int i = 0; i < 8; ++i) {
            int r = i * 4 + w;
            int x = lane * 4;
            int xs = x ^ (((r >> 3) & 1) << 4);
            float4 v = *(const float4*)(src + (size_t)r * ND + x);
            *(float4*)&tile[r * 256 + xs] = v;
        }
    }
    __syncthreads();

    int kl0 = (lane >> 4) * 8;
    int swz = ((lane >> 4) & 1) << 4;
    #pragma unroll
    for (int i = 0; i < 4; ++i) {
        int ns_local = i * 4 + w;
        int nl = ns_local * 16 + (lane & 15);
        int xsw = nl ^ swz;
        half8 v;
        #pragma unroll
        for (int j = 0; j < 8; ++j) v[j] = (_Float16)tile[(kl0 + j) * 256 + xsw];
        int ns = nb4 * 16 + ns_local;
        size_t unit = ((size_t)ns * KT32 + kt) * 64 + lane;
        *(half8*)(Ktf + unit * 8) = v;
    }
}

// ---- GEMM v4: P[o][b][n] = (w_o * h) @ K_o  (full opcode per block) ----
// grid (8 n-tiles of 128, 31 opcodes) = 248 blocks, 256 thr (4 waves),
// 64 KiB LDS -> 2 blocks/CU. Wave = M64 x N32 over all 32 K32 steps.
// A staged in two 512-d passes through the same LDS; acc persists.
// No cross-wave reduction, direct P store (P traffic halved vs KS=62).
__global__ __launch_bounds__(256) void gemm_k(
    const float* __restrict__ h, const _Float16* __restrict__ Ktf,
    const float* __restrict__ W, float* __restrict__ P, int step)
{
    __shared__ _Float16 lds_a[64 * 512];   // 64 KiB; half8-index: p*64 + b, p in [0,64)
    int nb = blockIdx.x;                   // 0..7
    int o  = blockIdx.y;                   // 0..30
    int tid = threadIdx.x;                 // 0..255
    int l = tid & 63, w = tid >> 6;        // w 0..3
    int ml = l & 15, q = l >> 4;
    int ns0 = nb * 8 + w * 2;              // two n-subtiles of 16 per wave
    int sb = tid >> 2, su = tid & 3;       // A-staging ids

    // B stream pointers (k-range = opcode o's 32 K32 steps)
    const half8* bp0 = (const half8*)Ktf + ((size_t)(ns0 + 0) * KT32 + (size_t)o * 32) * 64 + l;
    const half8* bp1 = (const half8*)Ktf + ((size_t)(ns0 + 1) * KT32 + (size_t)o * 32) * 64 + l;

    // first fragments issued before A staging (latency hidden under it)
    half8 bc0 = bp0[0], bc1 = bp1[0];

    floatx4 acc[2][4] = {};
    float wv = W[((size_t)sb * NSTEPS + step) * NO + o];

    #pragma unroll
    for (int p2 = 0; p2 < 2; ++p2) {
        // ---- stage A half-tile: fp32 h * w -> fp16, frag-ordered (64 b x 512 d) ----
        if (p2) __syncthreads();                 // pass-0 LDS reads done before overwrite
        {
            const float* hb = h + (size_t)sb * ND + p2 * 512;
            #pragma unroll
            for (int li = 0; li < 16; ++li) {
                int p = li * 4 + su;             // p in [0,64), d offset = p*8
                float4 x0 = *(const float4*)(hb + p * 8);
                float4 x1 = *(const float4*)(hb + p * 8 + 4);
                half8 v;
                v[0] = (_Float16)(x0.x * wv); v[1] = (_Float16)(x0.y * wv);
                v[2] = (_Float16)(x0.z * wv); v[3] = (_Float16)(x0.w * wv);
                v[4] = (_Float16)(x1.x * wv); v[5] = (_Float16)(x1.y * wv);
                v[6] = (_Float16)(x1.z * wv); v[7] = (_Float16)(x1.w * wv);
                *(half8*)&lds_a[(size_t)(p * 64 + sb) * 8] = v;
            }
        }
        __syncthreads();

        const half8* Ap = (const half8*)lds_a;
        #pragma unroll
        for (int s = 0; s < 16; ++s) {
            int gs = p2 * 16 + s;                // global K32 step 0..31
            half8 bn0, bn1;
            if (gs < 31) {                       // prefetch next (crosses pass boundary)
                bn0 = bp0[(size_t)(gs + 1) * 64];
                bn1 = bp1[(size_t)(gs + 1) * 64];
            }
            int abase = (s * 4 + q) * 64 + ml;
            half8 a0 = Ap[abase];
            half8 a1 = Ap[abase + 16];
            half8 a2 = Ap[abase + 32];
            half8 a3 = Ap[abase + 48];
            acc[0][0] = __builtin_amdgcn_mfma_f32_16x16x32_f16(a0, bc0, acc[0][0], 0, 0, 0);
            acc[0][1] = __builtin_amdgcn_mfma_f32_16x16x32_f16(a1, bc0, acc[0][1], 0, 0, 0);
            acc[0][2] = __builtin_amdgcn_mfma_f32_16x16x32_f16(a2, bc0, acc[0][2], 0, 0, 0);
            acc[0][3] = __builtin_amdgcn_mfma_f32_16x16x32_f16(a3, bc0, acc[0][3], 0, 0, 0);
            acc[1][0] = __builtin_amdgcn_mfma_f32_16x16x32_f16(a0, bc1, acc[1][0], 0, 0, 0);
            acc[1][1] = __builtin_amdgcn_mfma_f32_16x16x32_f16(a1, bc1, acc[1][1], 0, 0, 0);
            acc[1][2] = __builtin_amdgcn_mfma_f32_16x16x32_f16(a2, bc1, acc[1][2], 0, 0, 0);
            acc[1][3] = __builtin_amdgcn_mfma_f32_16x16x32_f16(a3, bc1, acc[1][3], 0, 0, 0);
            if (gs < 31) { bc0 = bn0; bc1 = bn1; }
        }
    }

    // ---- epilogue: C/D col = l&15, row = (l>>4)*4 + r (verified mapping) ----
    float* Po = P + (size_t)o * (NB * ND);
    #pragma unroll
    for (int t = 0; t < 2; ++t) {
        int n = (ns0 + t) * 16 + ml;
        #pragma unroll
        for (int mt = 0; mt < 4; ++mt) {
            #pragma unroll
            for (int r = 0; r < 4; ++r) {
                int b = mt * 16 + q * 4 + r;
                Po[(size_t)b * ND + n] = acc[t][mt][r];
            }
        }
    }
}

// ---- reduce KS=31 partials + gated update ----
// 512 blocks x 256 thr. Block owns 128 contiguous outputs (same b).
// Wave-pairs: waves {0,1} sum o in [0,16), waves {2,3} sum o in [16,31);
// each wave covers 64 of the 128 outputs (coalesced 256B wave-loads).
__global__ void update_k(const float* __restrict__ hin, const float* __restrict__ P,
                         const float* __restrict__ operands, float* __restrict__ hout,
                         int step)
{
    __shared__ float red[256];
    int tid = threadIdx.x;
    int w = tid >> 6, lane = tid & 63;
    int half = w >> 1;
    int j = (w & 1) * 64 + lane;              // output slot 0..127
    int g = blockIdx.x * 128 + j;
    const float* p = P + (size_t)(half * 16) * (NB * ND) + g;
    float s = 0.f;
    if (half == 0) {
        #pragma unroll
        for (int i = 0; i < 16; ++i) s += p[(size_t)i * (NB * ND)];
    } else {
        #pragma unroll
        for (int i = 0; i < 15; ++i) s += p[(size_t)i * (NB * ND)];
    }
    red[half * 128 + j] = s;
    __syncthreads();
    if (tid < 128) {
        float tot = red[tid] + red[tid + 128];
        int g2 = blockIdx.x * 128 + tid;
        int b = g2 >> 10;
        float gl = operands[((size_t)b * NSTEPS + step) * 4 + 3];
        float gt = 1.0f / (1.0f + expf(-gl));
        hout[g2] = gt * tot + (1.0f - gt) * hin[g2];
    }
}

extern "C" void kernel_launch(void* const* d_in, const int* in_sizes, int n_in,
                              void* d_out, int out_size, void* d_ws, size_t ws_size,
                              hipStream_t stream)
{
    const float* logits   = (const float*)d_in[0];  // (64,16,31)
    const float* operands = (const float*)d_in[1];  // (64,16,4)
    const float* signal   = (const float*)d_in[2];  // (64,1024)
    const float* opk      = (const float*)d_in[3];  // (31,1024,1024)
    float* out = (float*)d_out;
    char* ws = (char*)d_ws;

    size_t offW = 0;                                   // 128 KB
    size_t offP = 131072;                              // KS*64*1024*4 = 7.75 MB
    size_t offH = offP + (size_t)KS * NB * ND * 4;
    size_t offK = offH + 2ull * NB * ND * 4;           // Ktf: 62 MiB fp16

    float*    W  = (float*)(ws + offW);
    float*    P  = (float*)(ws + offP);
    float*    h0 = (float*)(ws + offH);
    float*    h1 = h0 + NB * ND;
    _Float16* Ktf = (_Float16*)(ws + offK);

    softmax_k<<<dim3(4), 256, 0, stream>>>(logits, W);
    kconv_k<<<dim3(3968), 256, 0, stream>>>(opk, Ktf);

    const float* hc = signal;
    float* hn = h0;
    for (int t = 0; t < NSTEPS; ++t) {
        gemm_k<<<dim3(8, KS), 256, 0, stream>>>(hc, Ktf, W, P, t);
        float* dst = (t == NSTEPS - 1) ? out : hn;
        update_k<<<dim3(512), 256, 0, stream>>>(hc, P, operands, dst, t);
        hc = dst;
        hn = (hn == h0) ? h1 : h0;
    }
}

// Round 11
// 491.727 us; speedup vs baseline: 7.0161x; 1.0979x over previous
//
#include <hip/hip_runtime.h>
#include <cstddef>
#include <cstdint>

#define NB 64
#define ND 1024
#define NO 31
#define NSTEPS 16
#define KS 62            // k-splits in P (k-chunk = 512 k-units, never crosses an opcode)
#define KT32 992         // total K32 steps = 31*1024/32

typedef _Float16 half8 __attribute__((ext_vector_type(8)));
typedef float floatx4 __attribute__((ext_vector_type(4)));

// ---------------- softmax over opcode logits: W[b][t][o] ----------------
__global__ void softmax_k(const float* __restrict__ logits, float* __restrict__ W) {
    int row = blockIdx.x * blockDim.x + threadIdx.x;  // row = b*16 + t
    if (row >= NB * NSTEPS) return;
    const float* x = logits + (size_t)row * NO;
    float m = -1e30f;
    for (int o = 0; o < NO; ++o) m = fmaxf(m, x[o]);
    float e[NO]; float s = 0.f;
    for (int o = 0; o < NO; ++o) { e[o] = expf(x[o] - m); s += e[o]; }
    float inv = 1.0f / s;
    float* wo = W + (size_t)row * NO;
    for (int o = 0; o < NO; ++o) wo[o] = e[o] * inv;
}

// ---- init16: signal -> h16 frag-order. unit u = d8*64 + b holds h[b][d8*8+j] ----
__global__ void init16_k(const float* __restrict__ h, _Float16* __restrict__ h16) {
    int u = blockIdx.x * 256 + threadIdx.x;   // 8192 units
    int d8 = u >> 6, b = u & 63;
    const float* src = h + (size_t)b * ND + d8 * 8;
    half8 v;
    #pragma unroll
    for (int j = 0; j < 8; ++j) v[j] = (_Float16)src[j];
    *(half8*)(h16 + (size_t)u * 8) = v;
}

// ---- kconv v2: coalesced tile transpose (unchanged, verified) ----
__global__ __launch_bounds__(256) void kconv_k(const float* __restrict__ K,
                                               _Float16* __restrict__ Ktf) {
    __shared__ float tile[32 * 256];           // 32 KB, swizzled cols
    int kt  = blockIdx.x >> 2;                 // 0..991
    int nb4 = blockIdx.x & 3;                  // 0..3 (256-col tile)
    int tid = threadIdx.x;
    int lane = tid & 63, w = tid >> 6;

    {
        const float* src = K + ((size_t)kt * 32) * ND + nb4 * 256;
        #pragma unroll
        for (int i = 0; i < 8; ++i) {
            int r = i * 4 + w;
            int x = lane * 4;
            int xs = x ^ (((r >> 3) & 1) << 4);
            float4 v = *(const float4*)(src + (size_t)r * ND + x);
            *(float4*)&tile[r * 256 + xs] = v;
        }
    }
    __syncthreads();

    int kl0 = (lane >> 4) * 8;
    int swz = ((lane >> 4) & 1) << 4;
    #pragma unroll
    for (int i = 0; i < 4; ++i) {
        int ns_local = i * 4 + w;
        int nl = ns_local * 16 + (lane & 15);
        int xsw = nl ^ swz;
        half8 v;
        #pragma unroll
        for (int j = 0; j < 8; ++j) v[j] = (_Float16)tile[(kl0 + j) * 256 + xsw];
        int ns = nb4 * 16 + ns_local;
        size_t unit = ((size_t)ns * KT32 + kt) * 64 + lane;
        *(half8*)(Ktf + unit * 8) = v;
    }
}

// ---- GEMM v5: P[ks][b][n] = (h @ B_chunk); w applied in epilogue ----
// grid (8 n-tiles of 128, 62 k-splits) = 496 blocks, 256 thr (4 waves).
// A = shared fp16 h (frag-order): staging is a pure 64 KB contiguous copy,
// zero VALU. Wave = M64 x N32 over 16 K32 steps, depth-2 B prefetch.
// Epilogue scales acc by w[b][o] (fp32) and stores P directly.
__global__ __launch_bounds__(256) void gemm_k(
    const _Float16* __restrict__ h16, const _Float16* __restrict__ Ktf,
    const float* __restrict__ W, float* __restrict__ P, int step)
{
    __shared__ _Float16 lds_a[64 * 512];   // 64 KiB; half8-unit: p*64 + b, p in [0,64)
    int nb = blockIdx.x;                   // 0..7
    int ks = blockIdx.y;                   // 0..61
    int tid = threadIdx.x;                 // 0..255
    int l = tid & 63, w = tid >> 6;        // w 0..3
    int o = ks >> 1;
    int ml = l & 15, q = l >> 4;
    int ns0 = nb * 8 + w * 2;              // two n-subtiles of 16 per wave

    // ---- B stream pointers; first two fragments issued before staging ----
    const half8* bp0 = (const half8*)Ktf + ((size_t)(ns0 + 0) * KT32 + (size_t)ks * 16) * 64 + l;
    const half8* bp1 = (const half8*)Ktf + ((size_t)(ns0 + 1) * KT32 + (size_t)ks * 16) * 64 + l;
    half8 c00 = bp0[0], c10 = bp1[0];
    half8 c01 = bp0[64], c11 = bp1[64];

    // ---- stage A: pure contiguous copy of the h16 half (64 KB), no VALU ----
    {
        const half8* hg = (const half8*)h16 + (size_t)(ks & 1) * 4096;
        #pragma unroll
        for (int i = 0; i < 16; ++i) {
            int u = i * 256 + tid;
            *(half8*)&lds_a[(size_t)u * 8] = hg[u];
        }
    }
    __syncthreads();

    const half8* Ap = (const half8*)lds_a;
    floatx4 acc[2][4] = {};
    #pragma unroll
    for (int s = 0; s < 16; ++s) {
        half8 f0, f1;
        if (s < 14) {                          // depth-2 prefetch (static indices)
            f0 = bp0[(size_t)(s + 2) * 64];
            f1 = bp1[(size_t)(s + 2) * 64];
        }
        int abase = (s * 4 + q) * 64 + ml;
        half8 a0 = Ap[abase];
        half8 a1 = Ap[abase + 16];
        half8 a2 = Ap[abase + 32];
        half8 a3 = Ap[abase + 48];
        acc[0][0] = __builtin_amdgcn_mfma_f32_16x16x32_f16(a0, c00, acc[0][0], 0, 0, 0);
        acc[0][1] = __builtin_amdgcn_mfma_f32_16x16x32_f16(a1, c00, acc[0][1], 0, 0, 0);
        acc[0][2] = __builtin_amdgcn_mfma_f32_16x16x32_f16(a2, c00, acc[0][2], 0, 0, 0);
        acc[0][3] = __builtin_amdgcn_mfma_f32_16x16x32_f16(a3, c00, acc[0][3], 0, 0, 0);
        acc[1][0] = __builtin_amdgcn_mfma_f32_16x16x32_f16(a0, c10, acc[1][0], 0, 0, 0);
        acc[1][1] = __builtin_amdgcn_mfma_f32_16x16x32_f16(a1, c10, acc[1][1], 0, 0, 0);
        acc[1][2] = __builtin_amdgcn_mfma_f32_16x16x32_f16(a2, c10, acc[1][2], 0, 0, 0);
        acc[1][3] = __builtin_amdgcn_mfma_f32_16x16x32_f16(a3, c10, acc[1][3], 0, 0, 0);
        if (s < 15) { c00 = c01; c10 = c11; }
        if (s < 14) { c01 = f0; c11 = f1; }
    }

    // ---- epilogue: scale by w[b][o]; C/D col = l&15, row = (l>>4)*4 + r ----
    float wtab[16];
    #pragma unroll
    for (int mt = 0; mt < 4; ++mt)
        #pragma unroll
        for (int r = 0; r < 4; ++r) {
            int b = mt * 16 + q * 4 + r;
            wtab[mt * 4 + r] = W[((size_t)b * NSTEPS + step) * NO + o];
        }
    float* Pks = P + (size_t)ks * (NB * ND);
    #pragma unroll
    for (int tt = 0; tt < 2; ++tt) {
        int n = (ns0 + tt) * 16 + ml;
        #pragma unroll
        for (int mt = 0; mt < 4; ++mt) {
            #pragma unroll
            for (int r = 0; r < 4; ++r) {
                int b = mt * 16 + q * 4 + r;
                Pks[(size_t)b * ND + n] = acc[tt][mt][r] * wtab[mt * 4 + r];
            }
        }
    }
}

// ---- reduce KS=62 partials + gated update; also emits h16 for next gemm ----
// 512 blocks x 256 thr. Block owns 128 contiguous outputs (same b).
// Wave-pairs: waves {0,1} sum ks [0,31), waves {2,3} sum ks [31,62).
__global__ void update_k(const float* __restrict__ hin, const float* __restrict__ P,
                         const float* __restrict__ operands, float* __restrict__ hout,
                         _Float16* __restrict__ h16n, int step)
{
    __shared__ float red[256];
    int tid = threadIdx.x;
    int w = tid >> 6, lane = tid & 63;
    int j = (w & 1) * 64 + lane;              // output slot 0..127
    int g = blockIdx.x * 128 + j;
    const float* p = P + (size_t)((w >> 1) * 31) * (NB * ND) + g;
    float s = 0.f;
    #pragma unroll
    for (int i = 0; i < 31; ++i) s += p[(size_t)i * (NB * ND)];
    red[(w >> 1) * 128 + j] = s;
    __syncthreads();
    if (tid < 128) {
        float tot = red[tid] + red[tid + 128];
        int g2 = blockIdx.x * 128 + tid;
        int b = g2 >> 10, n = g2 & 1023;
        float gl = operands[((size_t)b * NSTEPS + step) * 4 + 3];
        float gt = 1.0f / (1.0f + expf(-gl));
        float val = gt * tot + (1.0f - gt) * hin[g2];
        hout[g2] = val;
        h16n[((size_t)(n >> 3) * 64 + b) * 8 + (n & 7)] = (_Float16)val;
    }
}

extern "C" void kernel_launch(void* const* d_in, const int* in_sizes, int n_in,
                              void* d_out, int out_size, void* d_ws, size_t ws_size,
                              hipStream_t stream)
{
    const float* logits   = (const float*)d_in[0];  // (64,16,31)
    const float* operands = (const float*)d_in[1];  // (64,16,4)
    const float* signal   = (const float*)d_in[2];  // (64,1024)
    const float* opk      = (const float*)d_in[3];  // (31,1024,1024)
    float* out = (float*)d_out;
    char* ws = (char*)d_ws;

    size_t offW   = 0;                                   // 128 KB
    size_t offP   = 131072;                              // 62*64*1024*4 = 15.5 MB
    size_t offH   = offP + (size_t)KS * NB * ND * 4;     // h fp32 x2
    size_t offH16 = offH + 2ull * NB * ND * 4;           // h16 x2 (128 KB each)
    size_t offK   = offH16 + 2ull * NB * ND * 2;         // Ktf: 62 MiB fp16

    float*    W    = (float*)(ws + offW);
    float*    P    = (float*)(ws + offP);
    float*    h0   = (float*)(ws + offH);
    float*    h1   = h0 + NB * ND;
    _Float16* h16a = (_Float16*)(ws + offH16);
    _Float16* h16b = h16a + NB * ND;
    _Float16* Ktf  = (_Float16*)(ws + offK);

    softmax_k<<<dim3(4), 256, 0, stream>>>(logits, W);
    init16_k<<<dim3(32), 256, 0, stream>>>(signal, h16a);
    kconv_k<<<dim3(3968), 256, 0, stream>>>(opk, Ktf);

    const float* hc = signal;
    float* hn = h0;
    _Float16* h16c = h16a;
    _Float16* h16n = h16b;
    for (int t = 0; t < NSTEPS; ++t) {
        gemm_k<<<dim3(8, KS), 256, 0, stream>>>(h16c, Ktf, W, P, t);
        float* dst = (t == NSTEPS - 1) ? out : hn;
        update_k<<<dim3(512), 256, 0, stream>>>(hc, P, operands, dst, h16n, t);
        hc = dst;
        hn = (hn == h0) ? h1 : h0;
        _Float16* tmp = h16c; h16c = h16n; h16n = tmp;
    }
}